// Round 1
// baseline (186.578 us; speedup 1.0000x reference)
//
#include <hip/hip_runtime.h>

// Robust global pool: per 4096-elem slice, y* = argmin_y sum phi(y - x),
// phi = pseudo-Huber (alpha=1). Single-pass Taylor formulation (see R6):
//   S1 = sum w*r, S2 = sum r^3, S3 = -3 sum w*r^5, S4 = sum (12w^2-3)*r^7
//   (w = -x, r = (1+w^2)^-1/2), then 3 scalar Newton steps on the cubic model.
//
// R7: WAVE-PER-SLICE. R6 (block-per-slice, 4 loads/thread, LDS+barrier
// reduction) inferred at ~28 us vs the 21.3 us compulsory-read roofline
// (134 MB @ 6.3 TB/s). Changes:
//   - one 64-lane wave owns one slice: 16 contiguous float4 per lane,
//     16-deep independent load queue (16 KB in flight per wave, 256 KB/CU
//     at 16 waves/CU -- far above the ~9 KB needed to cover ~900 cy HBM
//     latency at 10.25 B/cy/CU).
//   - reduction is wave-only __shfl_xor: no LDS, no __syncthreads, no
//     cross-wave serialization; every wave independent, so sibling waves
//     keep the memory pipe busy through each wave's VALU tail.
//   - __launch_bounds__(256,4): 128-VGPR cap fits q[16] (64) + 8 split
//     accumulators + addressing with no spill.

__device__ __forceinline__ void acc4(float u, float& A, float& B,
                                     float& C, float& D) {
    float w  = -u;
    float r2 = fmaf(w, w, 1.0f);
    float r  = __builtin_amdgcn_rsqf(r2);   // single v_rsq_f32
    float rr = r * r;
    float r3 = rr * r;
    float r5 = r3 * rr;
    float r7 = r5 * rr;
    A = fmaf(w, r, A);                      // phi'
    B += r3;                                // phi''
    C = fmaf(w, r5, C);                     // -(1/3) phi'''
    float t12 = fmaf(12.0f, r2, -15.0f);    // 12w^2 - 3
    D = fmaf(t12, r7, D);                   // phi''''
}

__global__ __launch_bounds__(256, 4)
void robust_pool_kernel(const float* __restrict__ x, float* __restrict__ out,
                        int n_slices) {
    const int lane  = threadIdx.x & 63;
    const int slice = (blockIdx.x << 2) | (threadIdx.x >> 6);
    if (slice >= n_slices) return;

    const float4* gp =
        reinterpret_cast<const float4*>(x) + (size_t)slice * 1024 + lane;

    // 16 independent coalesced wave-loads (1 KB each), all in flight at once
    float4 q[16];
#pragma unroll
    for (int k = 0; k < 16; ++k) q[k] = gp[k * 64];

    // split accumulators break dependent FMA chains
    float A0 = 0, A1 = 0, B0 = 0, B1 = 0, C0 = 0, C1 = 0, D0 = 0, D1 = 0;
#pragma unroll
    for (int k = 0; k < 16; ++k) {
        acc4(q[k].x, A0, B0, C0, D0);
        acc4(q[k].y, A1, B1, C1, D1);
        acc4(q[k].z, A0, B0, C0, D0);
        acc4(q[k].w, A1, B1, C1, D1);
    }

    float A = A0 + A1, B = B0 + B1, C = C0 + C1, D = D0 + D1;
#pragma unroll
    for (int off = 32; off; off >>= 1) {
        A += __shfl_xor(A, off, 64);
        B += __shfl_xor(B, off, 64);
        C += __shfl_xor(C, off, 64);
        D += __shfl_xor(D, off, 64);
    }

    // cubic model F(y) = A + B y + c2 y^2 + c3 y^3; 3 scalar Newton steps
    const float c2 = -1.5f * C;             // S3/2 = (-3C)/2
    const float c3 = D * (1.0f / 6.0f);     // S4/6
    float y = -A * __builtin_amdgcn_rcpf(B);
#pragma unroll
    for (int it = 0; it < 3; ++it) {
        float F  = fmaf(fmaf(fmaf(c3, y, c2), y, B), y, A);
        float Fp = fmaf(fmaf(3.0f * c3, y, 2.0f * c2), y, B);
        y -= F * __builtin_amdgcn_rcpf(Fp);
    }

    if (lane == 0) out[slice] = y;
}

extern "C" void kernel_launch(void* const* d_in, const int* in_sizes, int n_in,
                              void* d_out, int out_size, void* d_ws, size_t ws_size,
                              hipStream_t stream) {
    const float* x = (const float*)d_in[0];
    float* out = (float*)d_out;
    const int n_slices = in_sizes[0] >> 12;        // 4096 elements per slice
    const int n_blocks = (n_slices + 3) >> 2;      // 4 waves (slices) per block
    robust_pool_kernel<<<n_blocks, 256, 0, stream>>>(x, out, n_slices);
}

// Round 2
// 185.786 us; speedup vs baseline: 1.0043x; 1.0043x over previous
//
#include <hip/hip_runtime.h>

// Robust global pool: per 4096-elem slice, y* = argmin_y sum phi(y - x),
// phi = pseudo-Huber (alpha=1). Single-pass Taylor formulation (see R6):
//   S1 = sum w*r, S2 = sum r^3, S3 = -3 sum w*r^5, S4 = sum (12w^2-3)*r^7
//   (w = -x, r = (1+w^2)^-1/2), then 3 scalar Newton steps on the cubic model.
//
// R8: wave-per-slice (barrier-free, R7) + full occupancy (R6).
// R7 regressed (+3.5 us) because __launch_bounds__(256,4) + q[16] (64 data
// VGPRs) capped occupancy at 16 waves/CU. Here:
//   - __launch_bounds__(256,8): 64-VGPR cap -> 32 waves/CU.
//   - 4-slot modulo-scheduled load pipeline: 4 float4 in flight per wave at
//     all times (4 KB/wave x 32 waves = 128 KB outstanding per CU, >> ~9 KB
//     needed to cover ~900 cy HBM latency at 10.25 B/cy/CU), only 16 data
//     VGPRs live -> ~40 total, no spill under the 64 cap.
//   - reduction stays wave-only __shfl_xor: no LDS, no __syncthreads.

__device__ __forceinline__ void acc4(float u, float& A, float& B,
                                     float& C, float& D) {
    float w  = -u;
    float r2 = fmaf(w, w, 1.0f);
    float r  = __builtin_amdgcn_rsqf(r2);   // single v_rsq_f32
    float rr = r * r;
    float r3 = rr * r;
    float r5 = r3 * rr;
    float r7 = r5 * rr;
    A = fmaf(w, r, A);                      // phi'
    B += r3;                                // phi''
    C = fmaf(w, r5, C);                     // -(1/3) phi'''
    float t12 = fmaf(12.0f, r2, -15.0f);    // 12w^2 - 3
    D = fmaf(t12, r7, D);                   // phi''''
}

__global__ __launch_bounds__(256, 8)
void robust_pool_kernel(const float* __restrict__ x, float* __restrict__ out,
                        int n_slices) {
    const int lane  = threadIdx.x & 63;
    const int slice = (blockIdx.x << 2) | (threadIdx.x >> 6);
    if (slice >= n_slices) return;

    const float4* gp =
        reinterpret_cast<const float4*>(x) + (size_t)slice * 1024 + lane;

    // 4-slot rotating load buffer, software-pipelined 4 deep
    float4 s0 = gp[0 * 64];
    float4 s1 = gp[1 * 64];
    float4 s2 = gp[2 * 64];
    float4 s3 = gp[3 * 64];

    // split accumulators break dependent FMA chains
    float A0 = 0, A1 = 0, B0 = 0, B1 = 0, C0 = 0, C1 = 0, D0 = 0, D1 = 0;

#define ACCQ(q)                         \
    acc4((q).x, A0, B0, C0, D0);        \
    acc4((q).y, A1, B1, C1, D1);        \
    acc4((q).z, A0, B0, C0, D0);        \
    acc4((q).w, A1, B1, C1, D1);

    // steady state: consume slot, refill with the load 4 ahead
    ACCQ(s0); s0 = gp[ 4 * 64];
    ACCQ(s1); s1 = gp[ 5 * 64];
    ACCQ(s2); s2 = gp[ 6 * 64];
    ACCQ(s3); s3 = gp[ 7 * 64];
    ACCQ(s0); s0 = gp[ 8 * 64];
    ACCQ(s1); s1 = gp[ 9 * 64];
    ACCQ(s2); s2 = gp[10 * 64];
    ACCQ(s3); s3 = gp[11 * 64];
    ACCQ(s0); s0 = gp[12 * 64];
    ACCQ(s1); s1 = gp[13 * 64];
    ACCQ(s2); s2 = gp[14 * 64];
    ACCQ(s3); s3 = gp[15 * 64];
    // epilogue: drain the last 4 slots
    ACCQ(s0);
    ACCQ(s1);
    ACCQ(s2);
    ACCQ(s3);
#undef ACCQ

    float A = A0 + A1, B = B0 + B1, C = C0 + C1, D = D0 + D1;
#pragma unroll
    for (int off = 32; off; off >>= 1) {
        A += __shfl_xor(A, off, 64);
        B += __shfl_xor(B, off, 64);
        C += __shfl_xor(C, off, 64);
        D += __shfl_xor(D, off, 64);
    }

    // cubic model F(y) = A + B y + c2 y^2 + c3 y^3; 3 scalar Newton steps
    const float c2 = -1.5f * C;             // S3/2 = (-3C)/2
    const float c3 = D * (1.0f / 6.0f);     // S4/6
    float y = -A * __builtin_amdgcn_rcpf(B);
#pragma unroll
    for (int it = 0; it < 3; ++it) {
        float F  = fmaf(fmaf(fmaf(c3, y, c2), y, B), y, A);
        float Fp = fmaf(fmaf(3.0f * c3, y, 2.0f * c2), y, B);
        y -= F * __builtin_amdgcn_rcpf(Fp);
    }

    if (lane == 0) out[slice] = y;
}

extern "C" void kernel_launch(void* const* d_in, const int* in_sizes, int n_in,
                              void* d_out, int out_size, void* d_ws, size_t ws_size,
                              hipStream_t stream) {
    const float* x = (const float*)d_in[0];
    float* out = (float*)d_out;
    const int n_slices = in_sizes[0] >> 12;        // 4096 elements per slice
    const int n_blocks = (n_slices + 3) >> 2;      // 4 waves (slices) per block
    robust_pool_kernel<<<n_blocks, 256, 0, stream>>>(x, out, n_slices);
}